// Round 14
// baseline (361.896 us; speedup 1.0000x reference)
//
#include <hip/hip_runtime.h>
#include <hip/hip_fp16.h>

// HyenaFilter = implicit-filter MLP (tiny) + FFT convolution.
// fftconv (fft_size=16384 >= 2L) == causal linear conv; bias folded into k[0].
// R13/R14: radix-16-in-registers. R12 showed conv is LDS-BW-bound (15.5 LDS
//   round-trips x 512KB = the whole 113us). Each thread now holds 16 points
//   in NAMED float2 scalars (arrays -> scratch, R8 lesson) and does two
//   radix-4 layers per LDS round-trip. Conv: 16->6 round-trips; the S=1
//   fwd stage + K-mult + S=1 inv stage fuse into one register pass.
//   (R14 = R13 resubmitted: container died before measuring R13.)

#define DIMC  768
#define BANDS 16
#define FO    64
#define LSEQ  8192
#define NF    16384
#define PI_F  3.14159265358979323846f
#define PI8   0.39269908169872414f   // pi/8

__device__ __forceinline__ int swz(int i) { return i ^ ((i >> 4) & 15); }

__device__ __forceinline__ float2 cmulm(float xr, float xi, float c, float s) {
    return make_float2(xr * c + xi * s, xi * c - xr * s);   // x*(c - i s)
}
__device__ __forceinline__ float2 cmulp(float xr, float xi, float c, float s) {
    return make_float2(xr * c - xi * s, xi * c + xr * s);   // x*(c + i s)
}
__device__ __forceinline__ void tw3(float th, float& c1, float& s1,
                                    float& c2, float& s2, float& c3, float& s3)
{
    c1 = __cosf(th); s1 = __sinf(th);
    c2 = c1 * c1 - s1 * s1; s2 = 2.f * c1 * s1;
    c3 = c1 * c2 - s1 * s2; s3 = c1 * s2 + s1 * c2;
}

// ---- radix-4 butterflies (in place, forward DIF / inverse DIT) -----------
__device__ __forceinline__ void bf4f_t(float2& a, float2& b, float2& c, float2& d,
                                       float c1, float s1, float c2, float s2,
                                       float c3, float s3)
{
    float Ar = a.x + c.x, Ai = a.y + c.y;
    float Br = a.x - c.x, Bi = a.y - c.y;
    float Cr = b.x + d.x, Ci = b.y + d.y;
    float Dr = b.y - d.y, Di = d.x - b.x;
    a = make_float2(Ar + Cr, Ai + Ci);
    b = cmulm(Br + Dr, Bi + Di, c1, s1);
    c = cmulm(Ar - Cr, Ai - Ci, c2, s2);
    d = cmulm(Br - Dr, Bi - Di, c3, s3);
}
__device__ __forceinline__ void bf4f(float2& a, float2& b, float2& c, float2& d, float th)
{
    float c1, s1, c2, s2, c3, s3; tw3(th, c1, s1, c2, s2, c3, s3);
    bf4f_t(a, b, c, d, c1, s1, c2, s2, c3, s3);
}
__device__ __forceinline__ void bf4zp(float2& a, float2& b, float2& c, float2& d, float th)
{   // forward, u2=u3=0 (zero-padded input); u0=a, u1=b
    float c1, s1, c2, s2, c3, s3; tw3(th, c1, s1, c2, s2, c3, s3);
    float2 u0 = a, u1 = b;
    a = make_float2(u0.x + u1.x, u0.y + u1.y);
    b = cmulm(u0.x + u1.y, u0.y - u1.x, c1, s1);
    c = cmulm(u0.x - u1.x, u0.y - u1.y, c2, s2);
    d = cmulm(u0.x - u1.y, u0.y + u1.x, c3, s3);
}
__device__ __forceinline__ void bf4f0(float2& a, float2& b, float2& c, float2& d)
{   // forward, twiddle = 1 (S=1)
    float Ar = a.x + c.x, Ai = a.y + c.y;
    float Br = a.x - c.x, Bi = a.y - c.y;
    float Cr = b.x + d.x, Ci = b.y + d.y;
    float Dr = b.y - d.y, Di = d.x - b.x;
    a = make_float2(Ar + Cr, Ai + Ci);
    b = make_float2(Br + Dr, Bi + Di);
    c = make_float2(Ar - Cr, Ai - Ci);
    d = make_float2(Br - Dr, Bi - Di);
}
__device__ __forceinline__ void bf4i_t(float2& a, float2& b, float2& c, float2& d,
                                       float c1, float s1, float c2, float s2,
                                       float c3, float s3)
{
    float2 V1 = cmulp(b.x, b.y, c1, s1);
    float2 V2 = cmulp(c.x, c.y, c2, s2);
    float2 V3 = cmulp(d.x, d.y, c3, s3);
    float e0r = a.x + V2.x, e0i = a.y + V2.y;
    float e1r = a.x - V2.x, e1i = a.y - V2.y;
    float f0r = V1.x + V3.x, f0i = V1.y + V3.y;
    float f1r = V1.x - V3.x, f1i = V1.y - V3.y;
    a = make_float2(e0r + f0r, e0i + f0i);
    b = make_float2(e1r - f1i, e1i + f1r);
    c = make_float2(e0r - f0r, e0i - f0i);
    d = make_float2(e1r + f1i, e1i - f1r);
}
__device__ __forceinline__ void bf4i(float2& a, float2& b, float2& c, float2& d, float th)
{
    float c1, s1, c2, s2, c3, s3; tw3(th, c1, s1, c2, s2, c3, s3);
    bf4i_t(a, b, c, d, c1, s1, c2, s2, c3, s3);
}
__device__ __forceinline__ void bf4i0(float2& a, float2& b, float2& c, float2& d)
{   // inverse, twiddle = 1 (S=1)
    float e0r = a.x + c.x, e0i = a.y + c.y;
    float e1r = a.x - c.x, e1i = a.y - c.y;
    float f0r = b.x + d.x, f0i = b.y + d.y;
    float f1r = b.x - d.x, f1i = b.y - d.y;
    a = make_float2(e0r + f0r, e0i + f0i);
    b = make_float2(e1r - f1i, e1i + f1r);
    c = make_float2(e0r - f0r, e0i - f0i);
    d = make_float2(e1r + f1i, e1i - f1r);
}
__device__ __forceinline__ void bf4it(float2& a, float2& b, float2 c, float2 d, float th)
{   // inverse, truncated: only first two outputs needed
    float c1, s1, c2, s2, c3, s3; tw3(th, c1, s1, c2, s2, c3, s3);
    float2 V1 = cmulp(b.x, b.y, c1, s1);
    float2 V2 = cmulp(c.x, c.y, c2, s2);
    float2 V3 = cmulp(d.x, d.y, c3, s3);
    float e0r = a.x + V2.x, e0i = a.y + V2.y;
    float e1r = a.x - V2.x, e1i = a.y - V2.y;
    float f0r = V1.x + V3.x, f0i = V1.y + V3.y;
    float f1r = V1.x - V3.x, f1i = V1.y - V3.y;
    a = make_float2(e0r + f0r, e0i + f0i);
    b = make_float2(e1r - f1i, e1i + f1r);
}

// ---- 16-register pass plumbing -------------------------------------------
#define DECL16 float2 r0,r1,r2,r3,r4,r5,r6,r7,r8,r9,r10,r11,r12,r13,r14,r15
#define LDS_RD16(P0, ST) do { \
    r0=L[swz(P0)];          r1=L[swz((P0)+(ST))];    r2=L[swz((P0)+2*(ST))];  r3=L[swz((P0)+3*(ST))]; \
    r4=L[swz((P0)+4*(ST))]; r5=L[swz((P0)+5*(ST))];  r6=L[swz((P0)+6*(ST))];  r7=L[swz((P0)+7*(ST))]; \
    r8=L[swz((P0)+8*(ST))]; r9=L[swz((P0)+9*(ST))];  r10=L[swz((P0)+10*(ST))];r11=L[swz((P0)+11*(ST))]; \
    r12=L[swz((P0)+12*(ST))];r13=L[swz((P0)+13*(ST))];r14=L[swz((P0)+14*(ST))];r15=L[swz((P0)+15*(ST))]; } while(0)
#define LDS_WR16(P0, ST) do { \
    L[swz(P0)]=r0;          L[swz((P0)+(ST))]=r1;    L[swz((P0)+2*(ST))]=r2;  L[swz((P0)+3*(ST))]=r3; \
    L[swz((P0)+4*(ST))]=r4; L[swz((P0)+5*(ST))]=r5;  L[swz((P0)+6*(ST))]=r6;  L[swz((P0)+7*(ST))]=r7; \
    L[swz((P0)+8*(ST))]=r8; L[swz((P0)+9*(ST))]=r9;  L[swz((P0)+10*(ST))]=r10;L[swz((P0)+11*(ST))]=r11; \
    L[swz((P0)+12*(ST))]=r12;L[swz((P0)+13*(ST))]=r13;L[swz((P0)+14*(ST))]=r14;L[swz((P0)+15*(ST))]=r15; } while(0)
// forward: layer A (stride 4*ST, th0+a*pi/8 on columns), layer B (stride ST, 4*th0 on rows)
#define LAYERA_F(TH0) do { \
    bf4f(r0,r4,r8,r12,(TH0)); bf4f(r1,r5,r9,r13,(TH0)+PI8); \
    bf4f(r2,r6,r10,r14,(TH0)+2.f*PI8); bf4f(r3,r7,r11,r15,(TH0)+3.f*PI8); } while(0)
#define LAYERB_F(TH) do { float C1,S1,C2,S2,C3,S3; tw3((TH),C1,S1,C2,S2,C3,S3); \
    bf4f_t(r0,r1,r2,r3,C1,S1,C2,S2,C3,S3);   bf4f_t(r4,r5,r6,r7,C1,S1,C2,S2,C3,S3); \
    bf4f_t(r8,r9,r10,r11,C1,S1,C2,S2,C3,S3); bf4f_t(r12,r13,r14,r15,C1,S1,C2,S2,C3,S3); } while(0)
#define LAYERA_ZP(TH0) do { \
    bf4zp(r0,r4,r8,r12,(TH0)); bf4zp(r1,r5,r9,r13,(TH0)+PI8); \
    bf4zp(r2,r6,r10,r14,(TH0)+2.f*PI8); bf4zp(r3,r7,r11,r15,(TH0)+3.f*PI8); } while(0)
// inverse: layer A (stride ST, 4*th0 on rows) FIRST, then layer B (stride 4*ST)
#define LAYERA_I(TH) do { float C1,S1,C2,S2,C3,S3; tw3((TH),C1,S1,C2,S2,C3,S3); \
    bf4i_t(r0,r1,r2,r3,C1,S1,C2,S2,C3,S3);   bf4i_t(r4,r5,r6,r7,C1,S1,C2,S2,C3,S3); \
    bf4i_t(r8,r9,r10,r11,C1,S1,C2,S2,C3,S3); bf4i_t(r12,r13,r14,r15,C1,S1,C2,S2,C3,S3); } while(0)
#define LAYERB_I(TH0) do { \
    bf4i(r0,r4,r8,r12,(TH0)); bf4i(r1,r5,r9,r13,(TH0)+PI8); \
    bf4i(r2,r6,r10,r14,(TH0)+2.f*PI8); bf4i(r3,r7,r11,r15,(TH0)+3.f*PI8); } while(0)
#define LAYERB_IT(TH0) do { \
    bf4it(r0,r4,r8,r12,(TH0)); bf4it(r1,r5,r9,r13,(TH0)+PI8); \
    bf4it(r2,r6,r10,r14,(TH0)+2.f*PI8); bf4it(r3,r7,r11,r15,(TH0)+3.f*PI8); } while(0)
#define FWD_PASS(P0, ST, TH0) do { LDS_RD16(P0,ST); LAYERA_F(TH0); LAYERB_F(4.f*(TH0)); LDS_WR16(P0,ST); } while(0)
#define INV_PASS(P0, ST, TH0) do { LDS_RD16(P0,ST); LAYERA_I(4.f*(TH0)); LAYERB_I(TH0); LDS_WR16(P0,ST); } while(0)

// ---------- Kernel 1: MLP hidden states h2[FO][LSEQ] ----------------------
__global__ void hidden_kernel(const float* __restrict__ W0, const float* __restrict__ b0,
                              const float* __restrict__ W1, const float* __restrict__ b1,
                              const float* __restrict__ W2, const float* __restrict__ b2,
                              const float* __restrict__ freq, float* __restrict__ hws)
{
    const int lane = threadIdx.x & 63;
    const int p = blockIdx.x * (blockDim.x >> 6) + (threadIdx.x >> 6);
    if (p >= LSEQ) return;
    const float tt = (float)p / (float)(LSEQ - 1);
    const float w  = 6.283185307179586f * (float)p / (float)LSEQ;

    float acc = b0[lane] + tt * W0[lane];
#pragma unroll
    for (int j = 0; j < BANDS; ++j) {
        float f = 1e-4f + (float)j * ((15.0f - 1e-4f) / 15.0f);
        float a = f * w;
        acc += __cosf(a)  * W0[(1 + j) * FO + lane];
        acc += -__sinf(a) * W0[(1 + BANDS + j) * FO + lane];
    }
    float h = __sinf(freq[lane] * acc);

    acc = b1[lane];
#pragma unroll
    for (int e = 0; e < FO; ++e) acc += __shfl(h, e) * W1[e * FO + lane];
    float h1 = __sinf(freq[lane] * acc);

    acc = b2[lane];
#pragma unroll
    for (int e = 0; e < FO; ++e) acc += __shfl(h1, e) * W2[e * FO + lane];
    float h2 = __sinf(freq[lane] * acc);

    hws[lane * LSEQ + p] = h2;
}

// ---------- Kernel 2: k[d][p] = (h2 . Wf) * (exp(-t|delta|)+0.05) ---------
#define DCHUNK 96
__global__ __launch_bounds__(256)
void filter_kernel(const float* __restrict__ hws, const float* __restrict__ Wf,
                   float* __restrict__ kws)
{
    __shared__ float hsh[256][65];
    const int tid = threadIdx.x;
    const int p  = blockIdx.x * 256 + tid;
    const int d0 = blockIdx.y * DCHUNK;
#pragma unroll
    for (int j = 0; j < FO; ++j) hsh[tid][j] = hws[j * LSEQ + p];
    __syncthreads();
    const float tt = (float)p / (float)(LSEQ - 1);
    const float min_decay = -3.0701134573253937f;
    const float max_decay = -15.350567286626971f;
    for (int dd = 0; dd < DCHUNK; ++dd) {
        const int d = d0 + dd;
        float acc = 0.f;
#pragma unroll
        for (int j = 0; j < FO; ++j) acc += hsh[tid][j] * Wf[j * DIMC + d];
        float delta = min_decay + (max_decay - min_decay) * ((float)d / (float)(DIMC - 1));
        float dec = __expf(-tt * fabsf(delta));
        kws[(size_t)d * LSEQ + p] = acc * (dec + 0.05f);
    }
}

// ---------- Kernel 3: K-hat = FFT(k)/N per channel (radix-16 passes) ------
template<int MODE>
__global__ __launch_bounds__(1024)
void kfft_kernel(const float* __restrict__ kf, const float* __restrict__ bias,
                 float2* __restrict__ KF, float* __restrict__ outbase)
{
    __shared__ float2 L[NF];
    const int d = blockIdx.x, t = threadIdx.x;
    const float* krow = kf + (size_t)d * LSEQ;
    DECL16;
    // P1: global load (zero-padded) + stages 4096,1024 + LDS write
    {
        float v = krow[t]; if (t == 0) v += bias[d];
        r0 = make_float2(v, 0.f);
        r1 = make_float2(krow[t + 1024], 0.f);
        r2 = make_float2(krow[t + 2048], 0.f);
        r3 = make_float2(krow[t + 3072], 0.f);
        r4 = make_float2(krow[t + 4096], 0.f);
        r5 = make_float2(krow[t + 5120], 0.f);
        r6 = make_float2(krow[t + 6144], 0.f);
        r7 = make_float2(krow[t + 7168], 0.f);
        const float th0 = (float)t * (PI_F / 8192.f);
        LAYERA_ZP(th0);
        LAYERB_F(4.f * th0);
        LDS_WR16(t, 1024);
    }
    // P2: stages 256,64
    __syncthreads();
    {
        const int P0 = ((t >> 6) << 10) | (t & 63);
        const float th0 = (float)(t & 63) * (PI_F / 512.f);
        FWD_PASS(P0, 64, th0);
    }
    // P3: stages 16,4
    __syncthreads();
    {
        const int P0 = ((t >> 2) << 6) | (t & 3);
        const float th0 = (float)(t & 3) * (PI_F / 32.f);
        FWD_PASS(P0, 4, th0);
    }
    // P4: stage 1 (trivial) + scale + global store
    __syncthreads();
    {
        const int base = t << 4;
        LDS_RD16(base, 1);
        bf4f0(r0, r1, r2, r3); bf4f0(r4, r5, r6, r7);
        bf4f0(r8, r9, r10, r11); bf4f0(r12, r13, r14, r15);
        const float invn = 1.0f / 16384.f;   // the ONLY 1/N in the pipeline
        if (MODE == 0) {
            float2* Kd = KF + (size_t)d * NF + base;
            Kd[0]=make_float2(r0.x*invn,r0.y*invn);   Kd[1]=make_float2(r1.x*invn,r1.y*invn);
            Kd[2]=make_float2(r2.x*invn,r2.y*invn);   Kd[3]=make_float2(r3.x*invn,r3.y*invn);
            Kd[4]=make_float2(r4.x*invn,r4.y*invn);   Kd[5]=make_float2(r5.x*invn,r5.y*invn);
            Kd[6]=make_float2(r6.x*invn,r6.y*invn);   Kd[7]=make_float2(r7.x*invn,r7.y*invn);
            Kd[8]=make_float2(r8.x*invn,r8.y*invn);   Kd[9]=make_float2(r9.x*invn,r9.y*invn);
            Kd[10]=make_float2(r10.x*invn,r10.y*invn);Kd[11]=make_float2(r11.x*invn,r11.y*invn);
            Kd[12]=make_float2(r12.x*invn,r12.y*invn);Kd[13]=make_float2(r13.x*invn,r13.y*invn);
            Kd[14]=make_float2(r14.x*invn,r14.y*invn);Kd[15]=make_float2(r15.x*invn,r15.y*invn);
        } else {
            __half2* H = (t < 512)
                ? (__half2*)(outbase + (size_t)d * LSEQ) + base
                : (__half2*)(outbase + (size_t)(DIMC + d) * LSEQ) + (base - 8192);
            H[0]=__floats2half2_rn(r0.x*invn,r0.y*invn);   H[1]=__floats2half2_rn(r1.x*invn,r1.y*invn);
            H[2]=__floats2half2_rn(r2.x*invn,r2.y*invn);   H[3]=__floats2half2_rn(r3.x*invn,r3.y*invn);
            H[4]=__floats2half2_rn(r4.x*invn,r4.y*invn);   H[5]=__floats2half2_rn(r5.x*invn,r5.y*invn);
            H[6]=__floats2half2_rn(r6.x*invn,r6.y*invn);   H[7]=__floats2half2_rn(r7.x*invn,r7.y*invn);
            H[8]=__floats2half2_rn(r8.x*invn,r8.y*invn);   H[9]=__floats2half2_rn(r9.x*invn,r9.y*invn);
            H[10]=__floats2half2_rn(r10.x*invn,r10.y*invn);H[11]=__floats2half2_rn(r11.x*invn,r11.y*invn);
            H[12]=__floats2half2_rn(r12.x*invn,r12.y*invn);H[13]=__floats2half2_rn(r13.x*invn,r13.y*invn);
            H[14]=__floats2half2_rn(r14.x*invn,r14.y*invn);H[15]=__floats2half2_rn(r15.x*invn,r15.y*invn);
        }
    }
}

// ---------- Kernel 4: conv — fwd FFT(x packed), K-mult, inv FFT -----------
template<int MODE>
__global__ __launch_bounds__(1024)
void conv_kernel(const float* __restrict__ x, const float2* __restrict__ KF,
                 float* __restrict__ out)
{
    __shared__ float2 L[NF];
    const int d = blockIdx.x, t = threadIdx.x;
    const float* x0 = x + (size_t)d * LSEQ;
    const float* x1 = x + (size_t)(DIMC + d) * LSEQ;
    float* o0 = out + (size_t)d * LSEQ;
    float* o1 = out + (size_t)(DIMC + d) * LSEQ;
    DECL16;
    // P1: global load (zero-padded, packed x0 + i x1) + stages 4096,1024
    {
        r0 = make_float2(x0[t],        x1[t]);
        r1 = make_float2(x0[t + 1024], x1[t + 1024]);
        r2 = make_float2(x0[t + 2048], x1[t + 2048]);
        r3 = make_float2(x0[t + 3072], x1[t + 3072]);
        r4 = make_float2(x0[t + 4096], x1[t + 4096]);
        r5 = make_float2(x0[t + 5120], x1[t + 5120]);
        r6 = make_float2(x0[t + 6144], x1[t + 6144]);
        r7 = make_float2(x0[t + 7168], x1[t + 7168]);
        const float th0 = (float)t * (PI_F / 8192.f);
        LAYERA_ZP(th0);
        LAYERB_F(4.f * th0);
        LDS_WR16(t, 1024);
    }
    // P2: fwd 256,64
    __syncthreads();
    {
        const int P0 = ((t >> 6) << 10) | (t & 63);
        const float th0 = (float)(t & 63) * (PI_F / 512.f);
        FWD_PASS(P0, 64, th0);
    }
    // P3: fwd 16,4
    __syncthreads();
    {
        const int P0 = ((t >> 2) << 6) | (t & 3);
        const float th0 = (float)(t & 3) * (PI_F / 32.f);
        FWD_PASS(P0, 4, th0);
    }
    // P4: fwd S=1 + K-hat multiply + inv S=1 (all trivial-twiddle, in regs)
    __syncthreads();
    {
        const int base = t << 4;
        LDS_RD16(base, 1);
        bf4f0(r0, r1, r2, r3); bf4f0(r4, r5, r6, r7);
        bf4f0(r8, r9, r10, r11); bf4f0(r12, r13, r14, r15);
        if (MODE == 0) {
            const float2* Kd = KF + (size_t)d * NF + base;
#define KMUL(J) { float2 k = Kd[J]; float2 z = r##J; \
    r##J = make_float2(z.x*k.x - z.y*k.y, z.x*k.y + z.y*k.x); }
            KMUL(0) KMUL(1) KMUL(2) KMUL(3) KMUL(4) KMUL(5) KMUL(6) KMUL(7)
            KMUL(8) KMUL(9) KMUL(10) KMUL(11) KMUL(12) KMUL(13) KMUL(14) KMUL(15)
#undef KMUL
        } else {
            const __half2* H = (t < 512)
                ? (const __half2*)(out + (size_t)d * LSEQ) + base
                : (const __half2*)(out + (size_t)(DIMC + d) * LSEQ) + (base - 8192);
#define KMULH(J) { float2 k = __half22float2(H[J]); float2 z = r##J; \
    r##J = make_float2(z.x*k.x - z.y*k.y, z.x*k.y + z.y*k.x); }
            KMULH(0) KMULH(1) KMULH(2) KMULH(3) KMULH(4) KMULH(5) KMULH(6) KMULH(7)
            KMULH(8) KMULH(9) KMULH(10) KMULH(11) KMULH(12) KMULH(13) KMULH(14) KMULH(15)
#undef KMULH
        }
        bf4i0(r0, r1, r2, r3); bf4i0(r4, r5, r6, r7);
        bf4i0(r8, r9, r10, r11); bf4i0(r12, r13, r14, r15);
        LDS_WR16(base, 1);
    }
    // P5: inv 4,16
    __syncthreads();
    {
        const int P0 = ((t >> 2) << 6) | (t & 3);
        const float th0 = (float)(t & 3) * (PI_F / 32.f);
        INV_PASS(P0, 4, th0);
    }
    // P6: inv 64,256
    __syncthreads();
    {
        const int P0 = ((t >> 6) << 10) | (t & 63);
        const float th0 = (float)(t & 63) * (PI_F / 512.f);
        INV_PASS(P0, 64, th0);
    }
    // P7: inv 1024,4096(truncated) + global store (outputs n < 8192 only)
    __syncthreads();
    {
        LDS_RD16(t, 1024);
        const float th0 = (float)t * (PI_F / 8192.f);
        LAYERA_I(4.f * th0);
        LAYERB_IT(th0);
        o0[t]        = r0.x; o1[t]        = r0.y;
        o0[t + 1024] = r1.x; o1[t + 1024] = r1.y;
        o0[t + 2048] = r2.x; o1[t + 2048] = r2.y;
        o0[t + 3072] = r3.x; o1[t + 3072] = r3.y;
        o0[t + 4096] = r4.x; o1[t + 4096] = r4.y;
        o0[t + 5120] = r5.x; o1[t + 5120] = r5.y;
        o0[t + 6144] = r6.x; o1[t + 6144] = r6.y;
        o0[t + 7168] = r7.x; o1[t + 7168] = r7.y;
    }
}

extern "C" void kernel_launch(void* const* d_in, const int* in_sizes, int n_in,
                              void* d_out, int out_size, void* d_ws, size_t ws_size,
                              hipStream_t stream)
{
    (void)in_sizes; (void)n_in; (void)out_size;
    const float* x    = (const float*)d_in[0];
    const float* W0   = (const float*)d_in[1];
    const float* b0   = (const float*)d_in[2];
    const float* W1   = (const float*)d_in[3];
    const float* b1   = (const float*)d_in[4];
    const float* W2   = (const float*)d_in[5];
    const float* b2   = (const float*)d_in[6];
    const float* Wf   = (const float*)d_in[7];
    const float* freq = (const float*)d_in[8];
    const float* bias = (const float*)d_in[9];
    float* out = (float*)d_out;

    float* hws = out;                            // h2 staged in out rows 0..63
    float* kws = out + (size_t)DIMC * LSEQ;      // k staged in out rows 768..1535

    hipLaunchKernelGGL(hidden_kernel, dim3(LSEQ / 4), dim3(256), 0, stream,
                       W0, b0, W1, b1, W2, b2, freq, hws);
    hipLaunchKernelGGL(filter_kernel, dim3(LSEQ / 256, DIMC / DCHUNK), dim3(256), 0, stream,
                       hws, Wf, kws);

    const size_t kbytes = (size_t)DIMC * NF * sizeof(float2);
    if (ws_size >= kbytes) {
        float2* KF = (float2*)d_ws;
        hipLaunchKernelGGL(kfft_kernel<0>, dim3(DIMC), dim3(1024), 0, stream,
                           kws, bias, KF, nullptr);
        hipLaunchKernelGGL(conv_kernel<0>, dim3(DIMC), dim3(1024), 0, stream,
                           x, KF, out);
    } else {
        hipLaunchKernelGGL(kfft_kernel<1>, dim3(DIMC), dim3(1024), 0, stream,
                           kws, bias, nullptr, out);
        hipLaunchKernelGGL(conv_kernel<1>, dim3(DIMC), dim3(1024), 0, stream,
                           x, nullptr, out);
    }
}

// Round 15
// 198.840 us; speedup vs baseline: 1.8200x; 1.8200x over previous
//
#include <hip/hip_runtime.h>
#include <hip/hip_fp16.h>

// HyenaFilter = implicit-filter MLP (tiny) + FFT convolution.
// fftconv (fft_size=16384 >= 2L) == causal linear conv; bias folded into k[0].
// R15: radix-8 stages (N=16384=8^4*4). R12 (radix-4, 113us conv) is
//   LDS-BW-bound; R14 (radix-16, 32 data VGPRs) spilled at the 64-VGPR cap
//   (WRITE 49->528MB). Radix-8 keeps only 8 live points (16 VGPRs, the
//   R12-proven budget) while consuming 3 bits per LDS round-trip:
//   conv 15.5 -> 9 half-passes. S=1 radix-4 (trivial twiddle) fuses with
//   the K-mult. Rolled m-loops, named scalars only (R8/R14 lessons).

#define DIMC  768
#define BANDS 16
#define FO    64
#define LSEQ  8192
#define NF    16384
#define PI_F  3.14159265358979323846f
#define RSQ2  0.70710678118654752f

__device__ __forceinline__ int swz(int i) { return i ^ ((i >> 4) & 15); }

__device__ __forceinline__ float2 cmulm(float xr, float xi, float c, float s) {
    return make_float2(xr * c + xi * s, xi * c - xr * s);   // x*(c - i s)
}
__device__ __forceinline__ float2 cmulp(float xr, float xi, float c, float s) {
    return make_float2(xr * c - xi * s, xi * c + xr * s);   // x*(c + i s)
}

#define TWCHAIN7(TH) \
    float c1=__cosf(TH), s1=__sinf(TH); \
    float c2=c1*c1-s1*s1, s2=2.f*c1*s1; \
    float c3=c1*c2-s1*s2, s3=s1*c2+c1*s2; \
    float c4=c2*c2-s2*s2, s4=2.f*c2*s2; \
    float c5=c2*c3-s2*s3, s5=s2*c3+c2*s3; \
    float c6=c3*c3-s3*s3, s6=2.f*c3*s3; \
    float c7=c3*c4-s3*s4, s7=s3*c4+c3*s4

// ---- full forward radix-8 DIF stage (in place, freq j -> slot p+jS) ------
template<int SH>
__device__ __forceinline__ void fwd8_stage(float2* L, int t)
{
    __syncthreads();
    const int S = 1 << SH;
#pragma unroll 1
    for (int m = 0; m < 2; ++m) {
        int b = t + (m << 10);
        int q = b & (S - 1);
        int p = ((b >> SH) << (SH + 3)) + q;
        float2 u0 = L[swz(p)];
        float2 u1 = L[swz(p + S)];
        float2 u2 = L[swz(p + 2 * S)];
        float2 u3 = L[swz(p + 3 * S)];
        float2 u4 = L[swz(p + 4 * S)];
        float2 u5 = L[swz(p + 5 * S)];
        float2 u6 = L[swz(p + 6 * S)];
        float2 u7 = L[swz(p + 7 * S)];
        float a0r=u0.x+u4.x, a0i=u0.y+u4.y, b0r=u0.x-u4.x, b0i=u0.y-u4.y;
        float a1r=u1.x+u5.x, a1i=u1.y+u5.y, b1r=u1.x-u5.x, b1i=u1.y-u5.y;
        float a2r=u2.x+u6.x, a2i=u2.y+u6.y, b2r=u2.x-u6.x, b2i=u2.y-u6.y;
        float a3r=u3.x+u7.x, a3i=u3.y+u7.y, b3r=u3.x-u7.x, b3i=u3.y-u7.y;
        // even 4-DFT (freqs 0,2,4,6)
        float e0r=a0r+a2r, e0i=a0i+a2i, e1r=a0r-a2r, e1i=a0i-a2i;
        float f0r=a1r+a3r, f0i=a1i+a3i, f1r=a1r-a3r, f1i=a1i-a3i;
        float y0r=e0r+f0r, y0i=e0i+f0i;
        float y4r=e0r-f0r, y4i=e0i-f0i;
        float y2r=e1r+f1i, y2i=e1i-f1r;       // e1 - i f1
        float y6r=e1r-f1i, y6i=e1i+f1r;       // e1 + i f1
        // odd: v_m = b_m * w8^m
        float v1r=(b1r+b1i)*RSQ2, v1i=(b1i-b1r)*RSQ2;     // *(1-i)/sqrt2
        float v2r=b2i,           v2i=-b2r;                // *(-i)
        float v3r=(b3i-b3r)*RSQ2, v3i=-(b3r+b3i)*RSQ2;    // *-(1+i)/sqrt2
        float g0r=b0r+v2r, g0i=b0i+v2i, g1r=b0r-v2r, g1i=b0i-v2i;
        float h0r=v1r+v3r, h0i=v1i+v3i, h1r=v1r-v3r, h1i=v1i-v3i;
        float y1r=g0r+h0r, y1i=g0i+h0i;
        float y5r=g0r-h0r, y5i=g0i-h0i;
        float y3r=g1r+h1i, y3i=g1i-h1r;       // g1 - i h1
        float y7r=g1r-h1i, y7i=g1i+h1r;       // g1 + i h1
        float th = (float)q * (PI_F / (4.0f * (float)S));
        TWCHAIN7(th);
        L[swz(p)]         = make_float2(y0r, y0i);
        L[swz(p + S)]     = cmulm(y1r, y1i, c1, s1);
        L[swz(p + 2 * S)] = cmulm(y2r, y2i, c2, s2);
        L[swz(p + 3 * S)] = cmulm(y3r, y3i, c3, s3);
        L[swz(p + 4 * S)] = cmulm(y4r, y4i, c4, s4);
        L[swz(p + 5 * S)] = cmulm(y5r, y5i, c5, s5);
        L[swz(p + 6 * S)] = cmulm(y6r, y6i, c6, s6);
        L[swz(p + 7 * S)] = cmulm(y7r, y7i, c7, s7);
    }
}

// first fwd stage (S=2048), zero-padded input: u4..u7 = 0 -> a_m = b_m = u_m
__device__ __forceinline__ void fwd8_first(float2* L, int q,
                                           float2 u0, float2 u1, float2 u2, float2 u3)
{
    float e0r=u0.x+u2.x, e0i=u0.y+u2.y, e1r=u0.x-u2.x, e1i=u0.y-u2.y;
    float f0r=u1.x+u3.x, f0i=u1.y+u3.y, f1r=u1.x-u3.x, f1i=u1.y-u3.y;
    float y0r=e0r+f0r, y0i=e0i+f0i;
    float y4r=e0r-f0r, y4i=e0i-f0i;
    float y2r=e1r+f1i, y2i=e1i-f1r;
    float y6r=e1r-f1i, y6i=e1i+f1r;
    float v1r=(u1.x+u1.y)*RSQ2, v1i=(u1.y-u1.x)*RSQ2;
    float v2r=u2.y,            v2i=-u2.x;
    float v3r=(u3.y-u3.x)*RSQ2, v3i=-(u3.x+u3.y)*RSQ2;
    float g0r=u0.x+v2r, g0i=u0.y+v2i, g1r=u0.x-v2r, g1i=u0.y-v2i;
    float h0r=v1r+v3r, h0i=v1i+v3i, h1r=v1r-v3r, h1i=v1i-v3i;
    float y1r=g0r+h0r, y1i=g0i+h0i;
    float y5r=g0r-h0r, y5i=g0i-h0i;
    float y3r=g1r+h1i, y3i=g1i-h1r;
    float y7r=g1r-h1i, y7i=g1i+h1r;
    float th = (float)q * (PI_F / 8192.0f);
    TWCHAIN7(th);
    L[swz(q)]         = make_float2(y0r, y0i);
    L[swz(q + 2048)]  = cmulm(y1r, y1i, c1, s1);
    L[swz(q + 4096)]  = cmulm(y2r, y2i, c2, s2);
    L[swz(q + 6144)]  = cmulm(y3r, y3i, c3, s3);
    L[swz(q + 8192)]  = cmulm(y4r, y4i, c4, s4);
    L[swz(q + 10240)] = cmulm(y5r, y5i, c5, s5);
    L[swz(q + 12288)] = cmulm(y6r, y6i, c6, s6);
    L[swz(q + 14336)] = cmulm(y7r, y7i, c7, s7);
}

// ---- inverse radix-8 DIT stage (conj twiddles, mirror of fwd8) -----------
template<int SH>
__device__ __forceinline__ void inv8_stage(float2* L, int t)
{
    __syncthreads();
    const int S = 1 << SH;
#pragma unroll 1
    for (int m = 0; m < 2; ++m) {
        int b = t + (m << 10);
        int q = b & (S - 1);
        int p = ((b >> SH) << (SH + 3)) + q;
        float th = (float)q * (PI_F / (4.0f * (float)S));
        TWCHAIN7(th);
        float2 y0 = L[swz(p)];
        float2 w;
        w = L[swz(p + S)];     float2 y1 = cmulp(w.x, w.y, c1, s1);
        w = L[swz(p + 2*S)];   float2 y2 = cmulp(w.x, w.y, c2, s2);
        w = L[swz(p + 3*S)];   float2 y3 = cmulp(w.x, w.y, c3, s3);
        w = L[swz(p + 4*S)];   float2 y4 = cmulp(w.x, w.y, c4, s4);
        w = L[swz(p + 5*S)];   float2 y5 = cmulp(w.x, w.y, c5, s5);
        w = L[swz(p + 6*S)];   float2 y6 = cmulp(w.x, w.y, c6, s6);
        w = L[swz(p + 7*S)];   float2 y7 = cmulp(w.x, w.y, c7, s7);
        // even IDFT4
        float E0r=y0.x+y4.x, E0i=y0.y+y4.y, F0r=y0.x-y4.x, F0i=y0.y-y4.y;
        float E1r=y2.x+y6.x, E1i=y2.y+y6.y;
        float F1r=-(y2.y-y6.y), F1i=y2.x-y6.x;            // i*(y2-y6)
        float a0r=E0r+E1r, a0i=E0i+E1i, a2r=E0r-E1r, a2i=E0i-E1i;
        float a1r=F0r+F1r, a1i=F0i+F1i, a3r=F0r-F1r, a3i=F0i-F1i;
        // odd IDFT4
        float G0r=y1.x+y5.x, G0i=y1.y+y5.y, H0r=y1.x-y5.x, H0i=y1.y-y5.y;
        float G1r=y3.x+y7.x, G1i=y3.y+y7.y;
        float H1r=-(y3.y-y7.y), H1i=y3.x-y7.x;            // i*(y3-y7)
        float v0r=G0r+G1r, v0i=G0i+G1i, v2r=G0r-G1r, v2i=G0i-G1i;
        float v1r=H0r+H1r, v1i=H0i+H1i, v3r=H0r-H1r, v3i=H0i-H1i;
        // b_m = v_m * conj(w8^m)
        float b0r=v0r, b0i=v0i;
        float b1r=(v1r-v1i)*RSQ2, b1i=(v1r+v1i)*RSQ2;     // *(1+i)/sqrt2
        float b2r=-v2i,          b2i=v2r;                 // *i
        float b3r=-(v3r+v3i)*RSQ2, b3i=(v3r-v3i)*RSQ2;    // *(-1+i)/sqrt2
        L[swz(p)]         = make_float2(a0r+b0r, a0i+b0i);
        L[swz(p + S)]     = make_float2(a1r+b1r, a1i+b1i);
        L[swz(p + 2 * S)] = make_float2(a2r+b2r, a2i+b2i);
        L[swz(p + 3 * S)] = make_float2(a3r+b3r, a3i+b3i);
        L[swz(p + 4 * S)] = make_float2(a0r-b0r, a0i-b0i);
        L[swz(p + 5 * S)] = make_float2(a1r-b1r, a1i-b1i);
        L[swz(p + 6 * S)] = make_float2(a2r-b2r, a2i-b2i);
        L[swz(p + 7 * S)] = make_float2(a3r-b3r, a3i-b3i);
    }
}

// trivial-twiddle radix-4 (S=1) fwd / inv on 4 consecutive points
__device__ __forceinline__ void bf4f0(float2& a, float2& b, float2& c, float2& d)
{
    float Ar = a.x + c.x, Ai = a.y + c.y;
    float Br = a.x - c.x, Bi = a.y - c.y;
    float Cr = b.x + d.x, Ci = b.y + d.y;
    float Dr = b.y - d.y, Di = d.x - b.x;
    a = make_float2(Ar + Cr, Ai + Ci);
    b = make_float2(Br + Dr, Bi + Di);
    c = make_float2(Ar - Cr, Ai - Ci);
    d = make_float2(Br - Dr, Bi - Di);
}
__device__ __forceinline__ void bf4i0(float2& a, float2& b, float2& c, float2& d)
{
    float e0r = a.x + c.x, e0i = a.y + c.y;
    float e1r = a.x - c.x, e1i = a.y - c.y;
    float f0r = b.x + d.x, f0i = b.y + d.y;
    float f1r = b.x - d.x, f1i = b.y - d.y;
    a = make_float2(e0r + f0r, e0i + f0i);
    b = make_float2(e1r - f1i, e1i + f1r);
    c = make_float2(e0r - f0r, e0i - f0i);
    d = make_float2(e1r + f1i, e1i - f1r);
}

// ---------- Kernel 1: MLP hidden states h2[FO][LSEQ] ----------------------
__global__ void hidden_kernel(const float* __restrict__ W0, const float* __restrict__ b0,
                              const float* __restrict__ W1, const float* __restrict__ b1,
                              const float* __restrict__ W2, const float* __restrict__ b2,
                              const float* __restrict__ freq, float* __restrict__ hws)
{
    const int lane = threadIdx.x & 63;
    const int p = blockIdx.x * (blockDim.x >> 6) + (threadIdx.x >> 6);
    if (p >= LSEQ) return;
    const float tt = (float)p / (float)(LSEQ - 1);
    const float w  = 6.283185307179586f * (float)p / (float)LSEQ;

    float acc = b0[lane] + tt * W0[lane];
#pragma unroll
    for (int j = 0; j < BANDS; ++j) {
        float f = 1e-4f + (float)j * ((15.0f - 1e-4f) / 15.0f);
        float a = f * w;
        acc += __cosf(a)  * W0[(1 + j) * FO + lane];
        acc += -__sinf(a) * W0[(1 + BANDS + j) * FO + lane];
    }
    float h = __sinf(freq[lane] * acc);

    acc = b1[lane];
#pragma unroll
    for (int e = 0; e < FO; ++e) acc += __shfl(h, e) * W1[e * FO + lane];
    float h1 = __sinf(freq[lane] * acc);

    acc = b2[lane];
#pragma unroll
    for (int e = 0; e < FO; ++e) acc += __shfl(h1, e) * W2[e * FO + lane];
    float h2 = __sinf(freq[lane] * acc);

    hws[lane * LSEQ + p] = h2;
}

// ---------- Kernel 2: k[d][p] = (h2 . Wf) * (exp(-t|delta|)+0.05) ---------
#define DCHUNK 96
__global__ __launch_bounds__(256)
void filter_kernel(const float* __restrict__ hws, const float* __restrict__ Wf,
                   float* __restrict__ kws)
{
    __shared__ float hsh[256][65];
    const int tid = threadIdx.x;
    const int p  = blockIdx.x * 256 + tid;
    const int d0 = blockIdx.y * DCHUNK;
#pragma unroll
    for (int j = 0; j < FO; ++j) hsh[tid][j] = hws[j * LSEQ + p];
    __syncthreads();
    const float tt = (float)p / (float)(LSEQ - 1);
    const float min_decay = -3.0701134573253937f;
    const float max_decay = -15.350567286626971f;
    for (int dd = 0; dd < DCHUNK; ++dd) {
        const int d = d0 + dd;
        float acc = 0.f;
#pragma unroll
        for (int j = 0; j < FO; ++j) acc += hsh[tid][j] * Wf[j * DIMC + d];
        float delta = min_decay + (max_decay - min_decay) * ((float)d / (float)(DIMC - 1));
        float dec = __expf(-tt * fabsf(delta));
        kws[(size_t)d * LSEQ + p] = acc * (dec + 0.05f);
    }
}

// ---------- Kernel 3: K-hat = FFT(k)/N per channel ------------------------
template<int MODE>
__global__ __launch_bounds__(1024)
void kfft_kernel(const float* __restrict__ kf, const float* __restrict__ bias,
                 float2* __restrict__ KF, float* __restrict__ outbase)
{
    __shared__ float2 L[NF];
    const int d = blockIdx.x, t = threadIdx.x;
    const float* krow = kf + (size_t)d * LSEQ;
    // P1: load + zero-padded radix-8 (S=2048)
#pragma unroll 1
    for (int m = 0; m < 2; ++m) {
        int q = t + (m << 10);
        float v0 = krow[q]; if (q == 0) v0 += bias[d];
        fwd8_first(L, q, make_float2(v0, 0.f),
                   make_float2(krow[q + 2048], 0.f),
                   make_float2(krow[q + 4096], 0.f),
                   make_float2(krow[q + 6144], 0.f));
    }
    fwd8_stage<8>(L, t);   // S=256
    fwd8_stage<5>(L, t);   // S=32
    fwd8_stage<2>(L, t);   // S=4
    // P5: trivial radix-4 S=1 + scale + store
    __syncthreads();
    const float invn = 1.0f / 16384.f;   // the ONLY 1/N
#pragma unroll 1
    for (int ch = 0; ch < 2; ++ch) {
        int n0 = (t << 4) + (ch << 3);
        float2 z0 = L[swz(n0)],     z1 = L[swz(n0 + 1)];
        float2 z2 = L[swz(n0 + 2)], z3 = L[swz(n0 + 3)];
        float2 z4 = L[swz(n0 + 4)], z5 = L[swz(n0 + 5)];
        float2 z6 = L[swz(n0 + 6)], z7 = L[swz(n0 + 7)];
        bf4f0(z0, z1, z2, z3); bf4f0(z4, z5, z6, z7);
        if (MODE == 0) {
            float2* Kd = KF + (size_t)d * NF + n0;
            Kd[0]=make_float2(z0.x*invn,z0.y*invn); Kd[1]=make_float2(z1.x*invn,z1.y*invn);
            Kd[2]=make_float2(z2.x*invn,z2.y*invn); Kd[3]=make_float2(z3.x*invn,z3.y*invn);
            Kd[4]=make_float2(z4.x*invn,z4.y*invn); Kd[5]=make_float2(z5.x*invn,z5.y*invn);
            Kd[6]=make_float2(z6.x*invn,z6.y*invn); Kd[7]=make_float2(z7.x*invn,z7.y*invn);
        } else {
            __half2* H = (n0 < 8192)
                ? (__half2*)(outbase + (size_t)d * LSEQ) + n0
                : (__half2*)(outbase + (size_t)(DIMC + d) * LSEQ) + (n0 - 8192);
            H[0]=__floats2half2_rn(z0.x*invn,z0.y*invn); H[1]=__floats2half2_rn(z1.x*invn,z1.y*invn);
            H[2]=__floats2half2_rn(z2.x*invn,z2.y*invn); H[3]=__floats2half2_rn(z3.x*invn,z3.y*invn);
            H[4]=__floats2half2_rn(z4.x*invn,z4.y*invn); H[5]=__floats2half2_rn(z5.x*invn,z5.y*invn);
            H[6]=__floats2half2_rn(z6.x*invn,z6.y*invn); H[7]=__floats2half2_rn(z7.x*invn,z7.y*invn);
        }
    }
}

// ---------- Kernel 4: conv — fwd FFT(x packed), K-mult, inv FFT -----------
template<int MODE>
__global__ __launch_bounds__(1024)
void conv_kernel(const float* __restrict__ x, const float2* __restrict__ KF,
                 float* __restrict__ out)
{
    __shared__ float2 L[NF];
    const int d = blockIdx.x, t = threadIdx.x;
    const float* x0 = x + (size_t)d * LSEQ;
    const float* x1 = x + (size_t)(DIMC + d) * LSEQ;
    float* o0 = out + (size_t)d * LSEQ;
    float* o1 = out + (size_t)(DIMC + d) * LSEQ;
    // P1: load packed x0 + i x1 + zero-padded radix-8 (S=2048)
#pragma unroll 1
    for (int m = 0; m < 2; ++m) {
        int q = t + (m << 10);
        fwd8_first(L, q, make_float2(x0[q], x1[q]),
                   make_float2(x0[q + 2048], x1[q + 2048]),
                   make_float2(x0[q + 4096], x1[q + 4096]),
                   make_float2(x0[q + 6144], x1[q + 6144]));
    }
    fwd8_stage<8>(L, t);
    fwd8_stage<5>(L, t);
    fwd8_stage<2>(L, t);
    // P5: fwd r4 S=1 + K-mult + inv r4 S=1 (all trivial twiddles)
    __syncthreads();
#pragma unroll 1
    for (int ch = 0; ch < 2; ++ch) {
        int n0 = (t << 4) + (ch << 3);
        float2 z0 = L[swz(n0)],     z1 = L[swz(n0 + 1)];
        float2 z2 = L[swz(n0 + 2)], z3 = L[swz(n0 + 3)];
        float2 z4 = L[swz(n0 + 4)], z5 = L[swz(n0 + 5)];
        float2 z6 = L[swz(n0 + 6)], z7 = L[swz(n0 + 7)];
        bf4f0(z0, z1, z2, z3); bf4f0(z4, z5, z6, z7);
        if (MODE == 0) {
            const float2* Kd = KF + (size_t)d * NF + n0;
#define KM(Z, J) { float2 k = Kd[J]; float zr = Z.x, zi = Z.y; \
    Z = make_float2(zr*k.x - zi*k.y, zr*k.y + zi*k.x); }
            KM(z0,0) KM(z1,1) KM(z2,2) KM(z3,3) KM(z4,4) KM(z5,5) KM(z6,6) KM(z7,7)
#undef KM
        } else {
            const __half2* H = (n0 < 8192)
                ? (const __half2*)(out + (size_t)d * LSEQ) + n0
                : (const __half2*)(out + (size_t)(DIMC + d) * LSEQ) + (n0 - 8192);
#define KMH(Z, J) { float2 k = __half22float2(H[J]); float zr = Z.x, zi = Z.y; \
    Z = make_float2(zr*k.x - zi*k.y, zr*k.y + zi*k.x); }
            KMH(z0,0) KMH(z1,1) KMH(z2,2) KMH(z3,3) KMH(z4,4) KMH(z5,5) KMH(z6,6) KMH(z7,7)
#undef KMH
        }
        bf4i0(z0, z1, z2, z3); bf4i0(z4, z5, z6, z7);
        L[swz(n0)]     = z0; L[swz(n0 + 1)] = z1;
        L[swz(n0 + 2)] = z2; L[swz(n0 + 3)] = z3;
        L[swz(n0 + 4)] = z4; L[swz(n0 + 5)] = z5;
        L[swz(n0 + 6)] = z6; L[swz(n0 + 7)] = z7;
    }
    inv8_stage<2>(L, t);   // S=4
    inv8_stage<5>(L, t);   // S=32
    inv8_stage<8>(L, t);   // S=256
    // P9: inv radix-8 S=2048, truncated (outputs n<8192) + global store
    __syncthreads();
#pragma unroll 1
    for (int m = 0; m < 2; ++m) {
        int q = t + (m << 10);
        float th = (float)q * (PI_F / 8192.0f);
        TWCHAIN7(th);
        float2 y0 = L[swz(q)];
        float2 w;
        w = L[swz(q + 2048)];  float2 y1 = cmulp(w.x, w.y, c1, s1);
        w = L[swz(q + 4096)];  float2 y2 = cmulp(w.x, w.y, c2, s2);
        w = L[swz(q + 6144)];  float2 y3 = cmulp(w.x, w.y, c3, s3);
        w = L[swz(q + 8192)];  float2 y4 = cmulp(w.x, w.y, c4, s4);
        w = L[swz(q + 10240)]; float2 y5 = cmulp(w.x, w.y, c5, s5);
        w = L[swz(q + 12288)]; float2 y6 = cmulp(w.x, w.y, c6, s6);
        w = L[swz(q + 14336)]; float2 y7 = cmulp(w.x, w.y, c7, s7);
        float E0r=y0.x+y4.x, E0i=y0.y+y4.y, F0r=y0.x-y4.x, F0i=y0.y-y4.y;
        float E1r=y2.x+y6.x, E1i=y2.y+y6.y;
        float F1r=-(y2.y-y6.y), F1i=y2.x-y6.x;
        float a0r=E0r+E1r, a0i=E0i+E1i, a2r=E0r-E1r, a2i=E0i-E1i;
        float a1r=F0r+F1r, a1i=F0i+F1i, a3r=F0r-F1r, a3i=F0i-F1i;
        float G0r=y1.x+y5.x, G0i=y1.y+y5.y, H0r=y1.x-y5.x, H0i=y1.y-y5.y;
        float G1r=y3.x+y7.x, G1i=y3.y+y7.y;
        float H1r=-(y3.y-y7.y), H1i=y3.x-y7.x;
        float v0r=G0r+G1r, v0i=G0i+G1i, v2r=G0r-G1r, v2i=G0i-G1i;
        float v1r=H0r+H1r, v1i=H0i+H1i, v3r=H0r-H1r, v3i=H0i-H1i;
        float b0r=v0r, b0i=v0i;
        float b1r=(v1r-v1i)*RSQ2, b1i=(v1r+v1i)*RSQ2;
        float b2r=-v2i,          b2i=v2r;
        float b3r=-(v3r+v3i)*RSQ2, b3i=(v3r-v3i)*RSQ2;
        o0[q]        = a0r + b0r;  o1[q]        = a0i + b0i;
        o0[q + 2048] = a1r + b1r;  o1[q + 2048] = a1i + b1i;
        o0[q + 4096] = a2r + b2r;  o1[q + 4096] = a2i + b2i;
        o0[q + 6144] = a3r + b3r;  o1[q + 6144] = a3i + b3i;
    }
}

extern "C" void kernel_launch(void* const* d_in, const int* in_sizes, int n_in,
                              void* d_out, int out_size, void* d_ws, size_t ws_size,
                              hipStream_t stream)
{
    (void)in_sizes; (void)n_in; (void)out_size;
    const float* x    = (const float*)d_in[0];
    const float* W0   = (const float*)d_in[1];
    const float* b0   = (const float*)d_in[2];
    const float* W1   = (const float*)d_in[3];
    const float* b1   = (const float*)d_in[4];
    const float* W2   = (const float*)d_in[5];
    const float* b2   = (const float*)d_in[6];
    const float* Wf   = (const float*)d_in[7];
    const float* freq = (const float*)d_in[8];
    const float* bias = (const float*)d_in[9];
    float* out = (float*)d_out;

    float* hws = out;                            // h2 staged in out rows 0..63
    float* kws = out + (size_t)DIMC * LSEQ;      // k staged in out rows 768..1535

    hipLaunchKernelGGL(hidden_kernel, dim3(LSEQ / 4), dim3(256), 0, stream,
                       W0, b0, W1, b1, W2, b2, freq, hws);
    hipLaunchKernelGGL(filter_kernel, dim3(LSEQ / 256, DIMC / DCHUNK), dim3(256), 0, stream,
                       hws, Wf, kws);

    const size_t kbytes = (size_t)DIMC * NF * sizeof(float2);
    if (ws_size >= kbytes) {
        float2* KF = (float2*)d_ws;
        hipLaunchKernelGGL(kfft_kernel<0>, dim3(DIMC), dim3(1024), 0, stream,
                           kws, bias, KF, nullptr);
        hipLaunchKernelGGL(conv_kernel<0>, dim3(DIMC), dim3(1024), 0, stream,
                           x, KF, out);
    } else {
        hipLaunchKernelGGL(kfft_kernel<1>, dim3(DIMC), dim3(1024), 0, stream,
                           kws, bias, nullptr, out);
        hipLaunchKernelGGL(conv_kernel<1>, dim3(DIMC), dim3(1024), 0, stream,
                           x, nullptr, out);
    }
}

// Round 16
// 157.622 us; speedup vs baseline: 2.2960x; 1.2615x over previous
//
#include <hip/hip_runtime.h>
#include <hip/hip_fp16.h>

// HyenaFilter = implicit-filter MLP (tiny) + FFT convolution.
// fftconv (fft_size=16384 >= 2L) == causal linear conv; bias folded into k[0].
// R15: radix-8 stages, conv 83us (LDS-bound model confirmed).
// R16: (1) filter j-outer/32-named-acc rewrite — old version did 6144 scalar
//      LDS reads/thread (~60us, the hidden #2 cost). (2) kfft pairs two REAL
//      k-rows per complex FFT (Hermitian unpack in scrambled-slot space;
//      slot = digit-reversed n, digits (8,8,8,8,4)). (3) K-hat as half2.

#define DIMC  768
#define BANDS 16
#define FO    64
#define LSEQ  8192
#define NF    16384
#define PI_F  3.14159265358979323846f
#define RSQ2  0.70710678118654752f

#define REP32(M) M(0) M(1) M(2) M(3) M(4) M(5) M(6) M(7) M(8) M(9) M(10) M(11) \
    M(12) M(13) M(14) M(15) M(16) M(17) M(18) M(19) M(20) M(21) M(22) M(23) \
    M(24) M(25) M(26) M(27) M(28) M(29) M(30) M(31)

__device__ __forceinline__ int swz(int i) { return i ^ ((i >> 4) & 15); }

__device__ __forceinline__ float2 cmulm(float xr, float xi, float c, float s) {
    return make_float2(xr * c + xi * s, xi * c - xr * s);   // x*(c - i s)
}
__device__ __forceinline__ float2 cmulp(float xr, float xi, float c, float s) {
    return make_float2(xr * c - xi * s, xi * c + xr * s);   // x*(c + i s)
}

#define TWCHAIN7(TH) \
    float c1=__cosf(TH), s1=__sinf(TH); \
    float c2=c1*c1-s1*s1, s2=2.f*c1*s1; \
    float c3=c1*c2-s1*s2, s3=s1*c2+c1*s2; \
    float c4=c2*c2-s2*s2, s4=2.f*c2*s2; \
    float c5=c2*c3-s2*s3, s5=s2*c3+c2*s3; \
    float c6=c3*c3-s3*s3, s6=2.f*c3*s3; \
    float c7=c3*c4-s3*s4, s7=s3*c4+c3*s4

// ---- full forward radix-8 DIF stage --------------------------------------
template<int SH>
__device__ __forceinline__ void fwd8_stage(float2* L, int t)
{
    __syncthreads();
    const int S = 1 << SH;
#pragma unroll 1
    for (int m = 0; m < 2; ++m) {
        int b = t + (m << 10);
        int q = b & (S - 1);
        int p = ((b >> SH) << (SH + 3)) + q;
        float2 u0 = L[swz(p)];
        float2 u1 = L[swz(p + S)];
        float2 u2 = L[swz(p + 2 * S)];
        float2 u3 = L[swz(p + 3 * S)];
        float2 u4 = L[swz(p + 4 * S)];
        float2 u5 = L[swz(p + 5 * S)];
        float2 u6 = L[swz(p + 6 * S)];
        float2 u7 = L[swz(p + 7 * S)];
        float a0r=u0.x+u4.x, a0i=u0.y+u4.y, b0r=u0.x-u4.x, b0i=u0.y-u4.y;
        float a1r=u1.x+u5.x, a1i=u1.y+u5.y, b1r=u1.x-u5.x, b1i=u1.y-u5.y;
        float a2r=u2.x+u6.x, a2i=u2.y+u6.y, b2r=u2.x-u6.x, b2i=u2.y-u6.y;
        float a3r=u3.x+u7.x, a3i=u3.y+u7.y, b3r=u3.x-u7.x, b3i=u3.y-u7.y;
        float e0r=a0r+a2r, e0i=a0i+a2i, e1r=a0r-a2r, e1i=a0i-a2i;
        float f0r=a1r+a3r, f0i=a1i+a3i, f1r=a1r-a3r, f1i=a1i-a3i;
        float y0r=e0r+f0r, y0i=e0i+f0i;
        float y4r=e0r-f0r, y4i=e0i-f0i;
        float y2r=e1r+f1i, y2i=e1i-f1r;
        float y6r=e1r-f1i, y6i=e1i+f1r;
        float v1r=(b1r+b1i)*RSQ2, v1i=(b1i-b1r)*RSQ2;
        float v2r=b2i,           v2i=-b2r;
        float v3r=(b3i-b3r)*RSQ2, v3i=-(b3r+b3i)*RSQ2;
        float g0r=b0r+v2r, g0i=b0i+v2i, g1r=b0r-v2r, g1i=b0i-v2i;
        float h0r=v1r+v3r, h0i=v1i+v3i, h1r=v1r-v3r, h1i=v1i-v3i;
        float y1r=g0r+h0r, y1i=g0i+h0i;
        float y5r=g0r-h0r, y5i=g0i-h0i;
        float y3r=g1r+h1i, y3i=g1i-h1r;
        float y7r=g1r-h1i, y7i=g1i+h1r;
        float th = (float)q * (PI_F / (4.0f * (float)S));
        TWCHAIN7(th);
        L[swz(p)]         = make_float2(y0r, y0i);
        L[swz(p + S)]     = cmulm(y1r, y1i, c1, s1);
        L[swz(p + 2 * S)] = cmulm(y2r, y2i, c2, s2);
        L[swz(p + 3 * S)] = cmulm(y3r, y3i, c3, s3);
        L[swz(p + 4 * S)] = cmulm(y4r, y4i, c4, s4);
        L[swz(p + 5 * S)] = cmulm(y5r, y5i, c5, s5);
        L[swz(p + 6 * S)] = cmulm(y6r, y6i, c6, s6);
        L[swz(p + 7 * S)] = cmulm(y7r, y7i, c7, s7);
    }
}

// first fwd stage (S=2048), zero-padded input: u4..u7 = 0
__device__ __forceinline__ void fwd8_first(float2* L, int q,
                                           float2 u0, float2 u1, float2 u2, float2 u3)
{
    float e0r=u0.x+u2.x, e0i=u0.y+u2.y, e1r=u0.x-u2.x, e1i=u0.y-u2.y;
    float f0r=u1.x+u3.x, f0i=u1.y+u3.y, f1r=u1.x-u3.x, f1i=u1.y-u3.y;
    float y0r=e0r+f0r, y0i=e0i+f0i;
    float y4r=e0r-f0r, y4i=e0i-f0i;
    float y2r=e1r+f1i, y2i=e1i-f1r;
    float y6r=e1r-f1i, y6i=e1i+f1r;
    float v1r=(u1.x+u1.y)*RSQ2, v1i=(u1.y-u1.x)*RSQ2;
    float v2r=u2.y,            v2i=-u2.x;
    float v3r=(u3.y-u3.x)*RSQ2, v3i=-(u3.x+u3.y)*RSQ2;
    float g0r=u0.x+v2r, g0i=u0.y+v2i, g1r=u0.x-v2r, g1i=u0.y-v2i;
    float h0r=v1r+v3r, h0i=v1i+v3i, h1r=v1r-v3r, h1i=v1i-v3i;
    float y1r=g0r+h0r, y1i=g0i+h0i;
    float y5r=g0r-h0r, y5i=g0i-h0i;
    float y3r=g1r+h1i, y3i=g1i-h1r;
    float y7r=g1r-h1i, y7i=g1i+h1r;
    float th = (float)q * (PI_F / 8192.0f);
    TWCHAIN7(th);
    L[swz(q)]         = make_float2(y0r, y0i);
    L[swz(q + 2048)]  = cmulm(y1r, y1i, c1, s1);
    L[swz(q + 4096)]  = cmulm(y2r, y2i, c2, s2);
    L[swz(q + 6144)]  = cmulm(y3r, y3i, c3, s3);
    L[swz(q + 8192)]  = cmulm(y4r, y4i, c4, s4);
    L[swz(q + 10240)] = cmulm(y5r, y5i, c5, s5);
    L[swz(q + 12288)] = cmulm(y6r, y6i, c6, s6);
    L[swz(q + 14336)] = cmulm(y7r, y7i, c7, s7);
}

// ---- inverse radix-8 DIT stage -------------------------------------------
template<int SH>
__device__ __forceinline__ void inv8_stage(float2* L, int t)
{
    __syncthreads();
    const int S = 1 << SH;
#pragma unroll 1
    for (int m = 0; m < 2; ++m) {
        int b = t + (m << 10);
        int q = b & (S - 1);
        int p = ((b >> SH) << (SH + 3)) + q;
        float th = (float)q * (PI_F / (4.0f * (float)S));
        TWCHAIN7(th);
        float2 y0 = L[swz(p)];
        float2 w;
        w = L[swz(p + S)];     float2 y1 = cmulp(w.x, w.y, c1, s1);
        w = L[swz(p + 2*S)];   float2 y2 = cmulp(w.x, w.y, c2, s2);
        w = L[swz(p + 3*S)];   float2 y3 = cmulp(w.x, w.y, c3, s3);
        w = L[swz(p + 4*S)];   float2 y4 = cmulp(w.x, w.y, c4, s4);
        w = L[swz(p + 5*S)];   float2 y5 = cmulp(w.x, w.y, c5, s5);
        w = L[swz(p + 6*S)];   float2 y6 = cmulp(w.x, w.y, c6, s6);
        w = L[swz(p + 7*S)];   float2 y7 = cmulp(w.x, w.y, c7, s7);
        float E0r=y0.x+y4.x, E0i=y0.y+y4.y, F0r=y0.x-y4.x, F0i=y0.y-y4.y;
        float E1r=y2.x+y6.x, E1i=y2.y+y6.y;
        float F1r=-(y2.y-y6.y), F1i=y2.x-y6.x;
        float a0r=E0r+E1r, a0i=E0i+E1i, a2r=E0r-E1r, a2i=E0i-E1i;
        float a1r=F0r+F1r, a1i=F0i+F1i, a3r=F0r-F1r, a3i=F0i-F1i;
        float G0r=y1.x+y5.x, G0i=y1.y+y5.y, H0r=y1.x-y5.x, H0i=y1.y-y5.y;
        float G1r=y3.x+y7.x, G1i=y3.y+y7.y;
        float H1r=-(y3.y-y7.y), H1i=y3.x-y7.x;
        float v0r=G0r+G1r, v0i=G0i+G1i, v2r=G0r-G1r, v2i=G0i-G1i;
        float v1r=H0r+H1r, v1i=H0i+H1i, v3r=H0r-H1r, v3i=H0i-H1i;
        float b0r=v0r, b0i=v0i;
        float b1r=(v1r-v1i)*RSQ2, b1i=(v1r+v1i)*RSQ2;
        float b2r=-v2i,          b2i=v2r;
        float b3r=-(v3r+v3i)*RSQ2, b3i=(v3r-v3i)*RSQ2;
        L[swz(p)]         = make_float2(a0r+b0r, a0i+b0i);
        L[swz(p + S)]     = make_float2(a1r+b1r, a1i+b1i);
        L[swz(p + 2 * S)] = make_float2(a2r+b2r, a2i+b2i);
        L[swz(p + 3 * S)] = make_float2(a3r+b3r, a3i+b3i);
        L[swz(p + 4 * S)] = make_float2(a0r-b0r, a0i-b0i);
        L[swz(p + 5 * S)] = make_float2(a1r-b1r, a1i-b1i);
        L[swz(p + 6 * S)] = make_float2(a2r-b2r, a2i-b2i);
        L[swz(p + 7 * S)] = make_float2(a3r-b3r, a3i-b3i);
    }
}

// trivial-twiddle radix-4 (S=1) fwd / inv
__device__ __forceinline__ void bf4f0(float2& a, float2& b, float2& c, float2& d)
{
    float Ar = a.x + c.x, Ai = a.y + c.y;
    float Br = a.x - c.x, Bi = a.y - c.y;
    float Cr = b.x + d.x, Ci = b.y + d.y;
    float Dr = b.y - d.y, Di = d.x - b.x;
    a = make_float2(Ar + Cr, Ai + Ci);
    b = make_float2(Br + Dr, Bi + Di);
    c = make_float2(Ar - Cr, Ai - Ci);
    d = make_float2(Br - Dr, Bi - Di);
}
__device__ __forceinline__ void bf4i0(float2& a, float2& b, float2& c, float2& d)
{
    float e0r = a.x + c.x, e0i = a.y + c.y;
    float e1r = a.x - c.x, e1i = a.y - c.y;
    float f0r = b.x + d.x, f0i = b.y + d.y;
    float f1r = b.x - d.x, f1i = b.y - d.y;
    a = make_float2(e0r + f0r, e0i + f0i);
    b = make_float2(e1r - f1i, e1i + f1r);
    c = make_float2(e0r - f0r, e0i - f0i);
    d = make_float2(e1r + f1i, e1i - f1r);
}

// ---------- Kernel 1: MLP hidden states h2[FO][LSEQ] ----------------------
__global__ void hidden_kernel(const float* __restrict__ W0, const float* __restrict__ b0,
                              const float* __restrict__ W1, const float* __restrict__ b1,
                              const float* __restrict__ W2, const float* __restrict__ b2,
                              const float* __restrict__ freq, float* __restrict__ hws)
{
    const int lane = threadIdx.x & 63;
    const int p = blockIdx.x * (blockDim.x >> 6) + (threadIdx.x >> 6);
    if (p >= LSEQ) return;
    const float tt = (float)p / (float)(LSEQ - 1);
    const float w  = 6.283185307179586f * (float)p / (float)LSEQ;

    float acc = b0[lane] + tt * W0[lane];
#pragma unroll
    for (int j = 0; j < BANDS; ++j) {
        float f = 1e-4f + (float)j * ((15.0f - 1e-4f) / 15.0f);
        float a = f * w;
        acc += __cosf(a)  * W0[(1 + j) * FO + lane];
        acc += -__sinf(a) * W0[(1 + BANDS + j) * FO + lane];
    }
    float h = __sinf(freq[lane] * acc);

    acc = b1[lane];
#pragma unroll
    for (int e = 0; e < FO; ++e) acc += __shfl(h, e) * W1[e * FO + lane];
    float h1 = __sinf(freq[lane] * acc);

    acc = b2[lane];
#pragma unroll
    for (int e = 0; e < FO; ++e) acc += __shfl(h1, e) * W2[e * FO + lane];
    float h2 = __sinf(freq[lane] * acc);

    hws[lane * LSEQ + p] = h2;
}

// ---------- Kernel 2: k[d][p] = (h2 . Wf) * (exp(-t|delta|)+0.05) ---------
// j-outer / 32-named-acc: h[j] read from LDS ONCE per 32-d chunk (192 LDS
// reads/thread vs old 6144); Wf index is lane-uniform -> s_load + SGPR FMA.
#define DCHUNK 96
__global__ __launch_bounds__(256)
void filter_kernel(const float* __restrict__ hws, const float* __restrict__ Wf,
                   float* __restrict__ kws)
{
    __shared__ float hsh[FO][257];   // [j][tid]; stride 257 -> conflict-free
    const int tid = threadIdx.x;
    const int p  = blockIdx.x * 256 + tid;
    const int d0 = blockIdx.y * DCHUNK;
#pragma unroll 1
    for (int j = 0; j < FO; ++j) hsh[j][tid] = hws[j * LSEQ + p];  // coalesced
    __syncthreads();
    const float tt = (float)p / (float)(LSEQ - 1);
    const float min_decay = -3.0701134573253937f;   // ln(0.01)/1.5
    const float max_decay = -15.350567286626971f;   // ln(0.01)/0.3
#pragma unroll 1
    for (int c = 0; c < DCHUNK / 32; ++c) {
        const int dc = d0 + c * 32;
#define DEFA(I) float a##I = 0.f;
        REP32(DEFA)
#undef DEFA
#pragma unroll 4
        for (int j = 0; j < FO; ++j) {
            float hj = hsh[j][tid];
            const float* Wj = Wf + j * DIMC + dc;   // lane-uniform address
#define FMA_(I) a##I = fmaf(hj, Wj[I], a##I);
            REP32(FMA_)
#undef FMA_
        }
#define ST_(I) { int d = dc + I; \
    float delta = min_decay + (max_decay - min_decay) * ((float)d / (float)(DIMC - 1)); \
    float dec = __expf(-tt * fabsf(delta)); \
    kws[(size_t)d * LSEQ + p] = a##I * (dec + 0.05f); }
        REP32(ST_)
#undef ST_
    }
}

// ---------- Kernel 3: K-hat for TWO real channels per complex FFT ---------
// z = k_{2g} + i k_{2g+1}; Hermitian unpack in scrambled-slot space:
// slot s <-> natural n via digit reversal, digits (8,8,8,8,4):
//   n = d0 + 8 d1 + 64 d2 + 512 d3 + 4096 e,  s = (d0<<11)|(d1<<8)|(d2<<5)|(d3<<2)|e
template<int MODE>
__global__ __launch_bounds__(1024)
void kfft_kernel(const float* __restrict__ kf, const float* __restrict__ bias,
                 __half2* __restrict__ KF, float* __restrict__ outbase)
{
    __shared__ float2 L[NF];
    const int g = blockIdx.x, t = threadIdx.x;
    const int da = 2 * g, db = 2 * g + 1;
    const float* ka = kf + (size_t)da * LSEQ;
    const float* kb = kf + (size_t)db * LSEQ;
#pragma unroll 1
    for (int m = 0; m < 2; ++m) {
        int q = t + (m << 10);
        float vr = ka[q], vi = kb[q];
        if (q == 0) { vr += bias[da]; vi += bias[db]; }
        fwd8_first(L, q, make_float2(vr, vi),
                   make_float2(ka[q + 2048], kb[q + 2048]),
                   make_float2(ka[q + 4096], kb[q + 4096]),
                   make_float2(ka[q + 6144], kb[q + 6144]));
    }
    fwd8_stage<8>(L, t);   // S=256
    fwd8_stage<5>(L, t);   // S=32
    fwd8_stage<2>(L, t);   // S=4
    // trivial radix-4 S=1, write back to LDS
    __syncthreads();
#pragma unroll 1
    for (int ch = 0; ch < 2; ++ch) {
        int n0 = (t << 4) + (ch << 3);
        float2 z0 = L[swz(n0)],     z1 = L[swz(n0 + 1)];
        float2 z2 = L[swz(n0 + 2)], z3 = L[swz(n0 + 3)];
        float2 z4 = L[swz(n0 + 4)], z5 = L[swz(n0 + 5)];
        float2 z6 = L[swz(n0 + 6)], z7 = L[swz(n0 + 7)];
        bf4f0(z0, z1, z2, z3); bf4f0(z4, z5, z6, z7);
        L[swz(n0)]     = z0; L[swz(n0 + 1)] = z1;
        L[swz(n0 + 2)] = z2; L[swz(n0 + 3)] = z3;
        L[swz(n0 + 4)] = z4; L[swz(n0 + 5)] = z5;
        L[swz(n0 + 6)] = z6; L[swz(n0 + 7)] = z7;
    }
    // Hermitian unpack + half2 store (1/N folded here, the ONLY scaling)
    __syncthreads();
    const float hn = 0.5f / 16384.f;
#pragma unroll 1
    for (int i = 0; i < 16; ++i) {
        int s = (i << 10) + t;
        int D0 = s >> 11, D1 = (s >> 8) & 7, D2 = (s >> 5) & 7, D3 = (s >> 2) & 7, E = s & 3;
        int n  = D0 + (D1 << 3) + (D2 << 6) + (D3 << 9) + (E << 12);
        int np = (16384 - n) & 16383;
        int sp = ((np & 7) << 11) | (((np >> 3) & 7) << 8) | (((np >> 6) & 7) << 5)
               | (((np >> 9) & 7) << 2) | ((np >> 12) & 3);
        float2 Zs = L[swz(s)];
        float2 Zp = L[swz(sp)];
        float kar = (Zs.x + Zp.x) * hn, kai = (Zs.y - Zp.y) * hn;   // A=(Z+conjZp)/2N
        float kbr = (Zs.y + Zp.y) * hn, kbi = (Zp.x - Zs.x) * hn;   // B=-i(Z-conjZp)/2N
        if (MODE == 0) {
            KF[(size_t)da * NF + s] = __floats2half2_rn(kar, kai);
            KF[(size_t)db * NF + s] = __floats2half2_rn(kbr, kbi);
        } else {
            __half2* Ha = (s < 8192)
                ? (__half2*)(outbase + (size_t)da * LSEQ) + s
                : (__half2*)(outbase + (size_t)(DIMC + da) * LSEQ) + (s - 8192);
            __half2* Hb = (s < 8192)
                ? (__half2*)(outbase + (size_t)db * LSEQ) + s
                : (__half2*)(outbase + (size_t)(DIMC + db) * LSEQ) + (s - 8192);
            *Ha = __floats2half2_rn(kar, kai);
            *Hb = __floats2half2_rn(kbr, kbi);
        }
    }
}

// ---------- Kernel 4: conv — fwd FFT(x packed), K-mult, inv FFT -----------
template<int MODE>
__global__ __launch_bounds__(1024)
void conv_kernel(const float* __restrict__ x, const __half2* __restrict__ KF,
                 float* __restrict__ out)
{
    __shared__ float2 L[NF];
    const int d = blockIdx.x, t = threadIdx.x;
    const float* x0 = x + (size_t)d * LSEQ;
    const float* x1 = x + (size_t)(DIMC + d) * LSEQ;
    float* o0 = out + (size_t)d * LSEQ;
    float* o1 = out + (size_t)(DIMC + d) * LSEQ;
#pragma unroll 1
    for (int m = 0; m < 2; ++m) {
        int q = t + (m << 10);
        fwd8_first(L, q, make_float2(x0[q], x1[q]),
                   make_float2(x0[q + 2048], x1[q + 2048]),
                   make_float2(x0[q + 4096], x1[q + 4096]),
                   make_float2(x0[q + 6144], x1[q + 6144]));
    }
    fwd8_stage<8>(L, t);
    fwd8_stage<5>(L, t);
    fwd8_stage<2>(L, t);
    // fwd r4 S=1 + K-mult (half2) + inv r4 S=1
    __syncthreads();
#pragma unroll 1
    for (int ch = 0; ch < 2; ++ch) {
        int n0 = (t << 4) + (ch << 3);
        float2 z0 = L[swz(n0)],     z1 = L[swz(n0 + 1)];
        float2 z2 = L[swz(n0 + 2)], z3 = L[swz(n0 + 3)];
        float2 z4 = L[swz(n0 + 4)], z5 = L[swz(n0 + 5)];
        float2 z6 = L[swz(n0 + 6)], z7 = L[swz(n0 + 7)];
        bf4f0(z0, z1, z2, z3); bf4f0(z4, z5, z6, z7);
        const __half2* H;
        if (MODE == 0) H = KF + (size_t)d * NF + n0;
        else H = (n0 < 8192)
            ? (const __half2*)(out + (size_t)d * LSEQ) + n0
            : (const __half2*)(out + (size_t)(DIMC + d) * LSEQ) + (n0 - 8192);
#define KMH(Z, J) { float2 k = __half22float2(H[J]); float zr = Z.x, zi = Z.y; \
    Z = make_float2(zr*k.x - zi*k.y, zr*k.y + zi*k.x); }
        KMH(z0,0) KMH(z1,1) KMH(z2,2) KMH(z3,3) KMH(z4,4) KMH(z5,5) KMH(z6,6) KMH(z7,7)
#undef KMH
        bf4i0(z0, z1, z2, z3); bf4i0(z4, z5, z6, z7);
        L[swz(n0)]     = z0; L[swz(n0 + 1)] = z1;
        L[swz(n0 + 2)] = z2; L[swz(n0 + 3)] = z3;
        L[swz(n0 + 4)] = z4; L[swz(n0 + 5)] = z5;
        L[swz(n0 + 6)] = z6; L[swz(n0 + 7)] = z7;
    }
    inv8_stage<2>(L, t);
    inv8_stage<5>(L, t);
    inv8_stage<8>(L, t);
    // inv radix-8 S=2048, truncated (outputs n<8192) + global store
    __syncthreads();
#pragma unroll 1
    for (int m = 0; m < 2; ++m) {
        int q = t + (m << 10);
        float th = (float)q * (PI_F / 8192.0f);
        TWCHAIN7(th);
        float2 y0 = L[swz(q)];
        float2 w;
        w = L[swz(q + 2048)];  float2 y1 = cmulp(w.x, w.y, c1, s1);
        w = L[swz(q + 4096)];  float2 y2 = cmulp(w.x, w.y, c2, s2);
        w = L[swz(q + 6144)];  float2 y3 = cmulp(w.x, w.y, c3, s3);
        w = L[swz(q + 8192)];  float2 y4 = cmulp(w.x, w.y, c4, s4);
        w = L[swz(q + 10240)]; float2 y5 = cmulp(w.x, w.y, c5, s5);
        w = L[swz(q + 12288)]; float2 y6 = cmulp(w.x, w.y, c6, s6);
        w = L[swz(q + 14336)]; float2 y7 = cmulp(w.x, w.y, c7, s7);
        float E0r=y0.x+y4.x, E0i=y0.y+y4.y, F0r=y0.x-y4.x, F0i=y0.y-y4.y;
        float E1r=y2.x+y6.x, E1i=y2.y+y6.y;
        float F1r=-(y2.y-y6.y), F1i=y2.x-y6.x;
        float a0r=E0r+E1r, a0i=E0i+E1i, a2r=E0r-E1r, a2i=E0i-E1i;
        float a1r=F0r+F1r, a1i=F0i+F1i, a3r=F0r-F1r, a3i=F0i-F1i;
        float G0r=y1.x+y5.x, G0i=y1.y+y5.y, H0r=y1.x-y5.x, H0i=y1.y-y5.y;
        float G1r=y3.x+y7.x, G1i=y3.y+y7.y;
        float H1r=-(y3.y-y7.y), H1i=y3.x-y7.x;
        float v0r=G0r+G1r, v0i=G0i+G1i, v2r=G0r-G1r, v2i=G0i-G1i;
        float v1r=H0r+H1r, v1i=H0i+H1i, v3r=H0r-H1r, v3i=H0i-H1i;
        float b0r=v0r, b0i=v0i;
        float b1r=(v1r-v1i)*RSQ2, b1i=(v1r+v1i)*RSQ2;
        float b2r=-v2i,          b2i=v2r;
        float b3r=-(v3r+v3i)*RSQ2, b3i=(v3r-v3i)*RSQ2;
        o0[q]        = a0r + b0r;  o1[q]        = a0i + b0i;
        o0[q + 2048] = a1r + b1r;  o1[q + 2048] = a1i + b1i;
        o0[q + 4096] = a2r + b2r;  o1[q + 4096] = a2i + b2i;
        o0[q + 6144] = a3r + b3r;  o1[q + 6144] = a3i + b3i;
    }
}

extern "C" void kernel_launch(void* const* d_in, const int* in_sizes, int n_in,
                              void* d_out, int out_size, void* d_ws, size_t ws_size,
                              hipStream_t stream)
{
    (void)in_sizes; (void)n_in; (void)out_size;
    const float* x    = (const float*)d_in[0];
    const float* W0   = (const float*)d_in[1];
    const float* b0   = (const float*)d_in[2];
    const float* W1   = (const float*)d_in[3];
    const float* b1   = (const float*)d_in[4];
    const float* W2   = (const float*)d_in[5];
    const float* b2   = (const float*)d_in[6];
    const float* Wf   = (const float*)d_in[7];
    const float* freq = (const float*)d_in[8];
    const float* bias = (const float*)d_in[9];
    float* out = (float*)d_out;

    float* hws = out;                            // h2 staged in out rows 0..63
    float* kws = out + (size_t)DIMC * LSEQ;      // k staged in out rows 768..1535

    hipLaunchKernelGGL(hidden_kernel, dim3(LSEQ / 4), dim3(256), 0, stream,
                       W0, b0, W1, b1, W2, b2, freq, hws);
    hipLaunchKernelGGL(filter_kernel, dim3(LSEQ / 256, DIMC / DCHUNK), dim3(256), 0, stream,
                       hws, Wf, kws);

    const size_t kbytes = (size_t)DIMC * NF * sizeof(__half2);   // 50 MB
    if (ws_size >= kbytes) {
        __half2* KF = (__half2*)d_ws;
        hipLaunchKernelGGL(kfft_kernel<0>, dim3(DIMC / 2), dim3(1024), 0, stream,
                           kws, bias, KF, nullptr);
        hipLaunchKernelGGL(conv_kernel<0>, dim3(DIMC), dim3(1024), 0, stream,
                           x, KF, out);
    } else {
        hipLaunchKernelGGL(kfft_kernel<1>, dim3(DIMC / 2), dim3(1024), 0, stream,
                           kws, bias, nullptr, out);
        hipLaunchKernelGGL(conv_kernel<1>, dim3(DIMC), dim3(1024), 0, stream,
                           x, nullptr, out);
    }
}